// Round 2
// baseline (58.142 us; speedup 1.0000x reference)
//
#include <hip/hip_runtime.h>

#define B_ 2
#define H_ 352
#define W_ 1216
#define HW_ (H_ * W_)      // 428032
#define K_ 9
#define NPIX (B_ * HW_)    // 856064
#define NT (NPIX / 4)      // 214016 threads, 4 pixels each
#define NB (NT / 256)      // 836 blocks exactly

typedef float v4 __attribute__((ext_vector_type(4)));

__global__ __launch_bounds__(256) void dcn_post_kernel(
    const float* __restrict__ depth,
    const float* __restrict__ weight,
    const float* __restrict__ offset,
    const float* __restrict__ wtap,
    const float* __restrict__ bias,
    float* __restrict__ out)
{
    const int q = blockIdx.x * 256 + threadIdx.x;      // quad id, exact grid
    const int b   = q / (HW_ / 4);
    const int rem = q - b * (HW_ / 4);
    const int y   = rem / (W_ / 4);
    const int x0  = (rem - y * (W_ / 4)) * 4;          // 16B-aligned column base
    const int p   = y * W_ + x0;

    const float* __restrict__ dpt = depth + b * HW_;
    const v4 dv = *reinterpret_cast<const v4*>(dpt + p);

    // kernel taps + bias (uniform scalar loads, hoisted)
    float wt[K_];
#pragma unroll
    for (int k = 0; k < K_; ++k) wt[k] = wtap[k];
    const float bv = bias[0];

    // modulation weights: 9 float4 plane loads + zero-mean
    const float* wbase = weight + (size_t)b * K_ * HW_ + p;
    v4 wg[K_];
    v4 ms = 0.f;
#pragma unroll
    for (int k = 0; k < K_; ++k) {
        wg[k] = *reinterpret_cast<const v4*>(wbase + k * HW_);
        ms += wg[k];
    }
    ms *= (1.f / 9.f);

    const float* obase = offset + (size_t)b * 2 * K_ * HW_ + p;

    v4 acc = 0.f;
#pragma unroll
    for (int k = 0; k < K_; ++k) {
        const v4 dy4 = *reinterpret_cast<const v4*>(obase + (2 * k) * HW_);
        const v4 dx4 = *reinterpret_cast<const v4*>(obase + (2 * k + 1) * HW_);
        const float ky = (float)(y + (k / 3) - 1);
        const float wk = wt[k];
#pragma unroll
        for (int i = 0; i < 4; ++i) {
            const float py = ky + dy4[i];
            const float px = (float)(x0 + i + (k % 3) - 1) + dx4[i];
            const float y0f = floorf(py);
            const float x0f = floorf(px);
            const float fy = py - y0f;
            const float fx = px - x0f;
            const int yi0 = (int)y0f, xi0 = (int)x0f;
            const int yi1 = yi0 + 1,  xi1 = xi0 + 1;
            const bool vy0 = (unsigned)yi0 < (unsigned)H_;
            const bool vy1 = (unsigned)yi1 < (unsigned)H_;
            const bool vx0 = (unsigned)xi0 < (unsigned)W_;
            const bool vx1 = (unsigned)xi1 < (unsigned)W_;
            const int r0 = yi0 * W_;
            const int r1 = r0 + W_;
            const float v00 = (vy0 && vx0) ? dpt[r0 + xi0] : 0.f;
            const float v01 = (vy0 && vx1) ? dpt[r0 + xi1] : 0.f;
            const float v10 = (vy1 && vx0) ? dpt[r1 + xi0] : 0.f;
            const float v11 = (vy1 && vx1) ? dpt[r1 + xi1] : 0.f;
            const float gy = 1.f - fy, gx = 1.f - fx;
            const float val = v00 * gy * gx + v01 * gy * fx
                            + v10 * fy * gx + v11 * fy * fx;
            acc[i] += (wg[k][i] - ms[i]) * wk * val;
        }
    }

    const v4 res = acc + bv + dv;
    *reinterpret_cast<v4*>(out + b * HW_ + p) = res;
}

extern "C" void kernel_launch(void* const* d_in, const int* in_sizes, int n_in,
                              void* d_out, int out_size, void* d_ws, size_t ws_size,
                              hipStream_t stream) {
    const float* depth  = (const float*)d_in[0];
    const float* weight = (const float*)d_in[1];
    const float* offset = (const float*)d_in[2];
    const float* wtap   = (const float*)d_in[3];
    const float* bias   = (const float*)d_in[4];
    float* out = (float*)d_out;

    dim3 grid(NB), block(256);
    hipLaunchKernelGGL(dcn_post_kernel, grid, block, 0, stream,
                       depth, weight, offset, wtap, bias, out);
}

// Round 3
// 29.429 us; speedup vs baseline: 1.9757x; 1.9757x over previous
//
#include <hip/hip_runtime.h>

#define B_ 2
#define H_ 352
#define W_ 1216
#define HW_ (H_ * W_)      // 428032
#define K_ 9
#define TW 64              // tile width (pixels)
#define TH 4               // tile height
#define SR 16              // staged rows  (TH + 2*SOFF)
#define SC 76              // staged cols  (TW + 2*SOFF)
#define SOFF 6             // halo margin
#define NBX (W_ / TW)      // 19
#define NBY (H_ / TH)      // 88
#define NBLK (B_ * NBX * NBY)  // 3344

__global__ __launch_bounds__(256) void dcn_post_kernel(
    const float* __restrict__ depth,
    const float* __restrict__ weight,
    const float* __restrict__ offset,
    const float* __restrict__ wtap,
    const float* __restrict__ bias,
    float* __restrict__ out)
{
    __shared__ float sm[SR * SC];   // 4864 B

    const int bid = blockIdx.x;
    const int b   = bid / (NBX * NBY);
    const int r2  = bid - b * (NBX * NBY);
    const int by  = r2 / NBX;
    const int bx  = r2 - by * NBX;
    const int tid = threadIdx.x;
    const int tx  = tid & (TW - 1);
    const int ty  = tid >> 6;

    const int y  = by * TH + ty;
    const int x  = bx * TW + tx;
    const int oy = by * TH - SOFF;
    const int ox = bx * TW - SOFF;
    const int p  = y * W_ + x;

    const float* __restrict__ dpt = depth + b * HW_;

    // ---- stage 16x76 depth halo into LDS, zeros outside the image ----
    for (int i = tid; i < SR * SC; i += 256) {
        const int r = i / SC;
        const int c = i - r * SC;
        const int gy = oy + r;
        const int gx = ox + c;
        float v = 0.f;
        if ((unsigned)gy < (unsigned)H_ && (unsigned)gx < (unsigned)W_)
            v = dpt[gy * W_ + gx];
        sm[i] = v;
    }

    // hoisted uniform params + streamed per-pixel loads (overlap the barrier)
    float wt[K_];
#pragma unroll
    for (int k = 0; k < K_; ++k) wt[k] = wtap[k];
    const float bv   = bias[0];
    const float dval = dpt[p];

    float wg[K_];
    float m = 0.f;
    const float* wbase = weight + (size_t)b * K_ * HW_ + p;
#pragma unroll
    for (int k = 0; k < K_; ++k) {
        wg[k] = wbase[k * HW_];
        m += wg[k];
    }
    m *= (1.f / 9.f);

    __syncthreads();

    const float* obase = offset + (size_t)b * 2 * K_ * HW_ + p;

    float acc = 0.f;
#pragma unroll
    for (int k = 0; k < K_; ++k) {
        const float dy = obase[(2 * k) * HW_];
        const float dx = obase[(2 * k + 1) * HW_];
        const float py = (float)(y + (k / 3) - 1) + dy;
        const float px = (float)(x + (k % 3) - 1) + dx;
        const float y0f = floorf(py);
        const float x0f = floorf(px);
        const float fy = py - y0f;
        const float fx = px - x0f;
        const int yi0 = (int)y0f, xi0 = (int)x0f;

        const int ly = yi0 - oy;           // need [0, SR-2]
        const int lx = xi0 - ox;           // need [0, SC-2]
        float v00, v01, v10, v11;
        if ((unsigned)ly <= (SR - 2) && (unsigned)lx <= (SC - 2)) {
            const float* s = sm + ly * SC + lx;
            v00 = s[0];
            v01 = s[1];
            v10 = s[SC];
            v11 = s[SC + 1];
        } else {
            // rare fallback (|offset| > ~5): zero-padded global gather
            const int yi1 = yi0 + 1, xi1 = xi0 + 1;
            const bool vy0 = (unsigned)yi0 < (unsigned)H_;
            const bool vy1 = (unsigned)yi1 < (unsigned)H_;
            const bool vx0 = (unsigned)xi0 < (unsigned)W_;
            const bool vx1 = (unsigned)xi1 < (unsigned)W_;
            const int r0 = yi0 * W_;
            const int r1 = r0 + W_;
            v00 = (vy0 && vx0) ? dpt[r0 + xi0] : 0.f;
            v01 = (vy0 && vx1) ? dpt[r0 + xi1] : 0.f;
            v10 = (vy1 && vx0) ? dpt[r1 + xi0] : 0.f;
            v11 = (vy1 && vx1) ? dpt[r1 + xi1] : 0.f;
        }

        const float gy = 1.f - fy, gx = 1.f - fx;
        const float val = v00 * gy * gx + v01 * gy * fx
                        + v10 * fy * gx + v11 * fy * fx;
        acc += (wg[k] - m) * wt[k] * val;
    }

    out[b * HW_ + p] = acc + bv + dval;
}

extern "C" void kernel_launch(void* const* d_in, const int* in_sizes, int n_in,
                              void* d_out, int out_size, void* d_ws, size_t ws_size,
                              hipStream_t stream) {
    const float* depth  = (const float*)d_in[0];
    const float* weight = (const float*)d_in[1];
    const float* offset = (const float*)d_in[2];
    const float* wtap   = (const float*)d_in[3];
    const float* bias   = (const float*)d_in[4];
    float* out = (float*)d_out;

    dim3 grid(NBLK), block(256);
    hipLaunchKernelGGL(dcn_post_kernel, grid, block, 0, stream,
                       depth, weight, offset, wtap, bias, out);
}

// Round 4
// 24.995 us; speedup vs baseline: 2.3261x; 1.1774x over previous
//
#include <hip/hip_runtime.h>

#define B_ 2
#define H_ 352
#define W_ 1216
#define HW_ (H_ * W_)      // 428032
#define K_ 9
#define TW 64              // tile width (pixels)
#define TH 4               // tile height
#define SOFF 8             // halo margin (8 => 16B-aligned halo base)
#define SR (TH + 2 * SOFF) // 20 staged rows
#define SC (TW + 2 * SOFF) // 80 staged cols (multiple of 4)
#define NBX (W_ / TW)      // 19
#define NBY (H_ / TH)      // 88
#define NBLK (B_ * NBX * NBY)  // 3344
#define NV4 (SR * (SC / 4))    // 400 float4 stage elements

typedef float v4 __attribute__((ext_vector_type(4)));

__global__ __launch_bounds__(256) void dcn_post_kernel(
    const float* __restrict__ depth,
    const float* __restrict__ weight,
    const float* __restrict__ offset,
    const float* __restrict__ wtap,
    const float* __restrict__ bias,
    float* __restrict__ out)
{
    __shared__ float sm[SR * SC];   // 6400 B

    const int bid = blockIdx.x;
    const int b   = bid / (NBX * NBY);
    const int r2  = bid - b * (NBX * NBY);
    const int by  = r2 / NBX;
    const int bx  = r2 - by * NBX;
    const int tid = threadIdx.x;
    const int tx  = tid & (TW - 1);
    const int ty  = tid >> 6;

    const int y  = by * TH + ty;
    const int x  = bx * TW + tx;
    const int oy = by * TH - SOFF;
    const int ox = bx * TW - SOFF;   // element offset; ox*4 bytes is 16B-aligned
    const int p  = y * W_ + x;

    const float* __restrict__ dpt = depth + b * HW_;

    // ---- stage 20x80 depth halo into LDS via predicated float4 ----
#pragma unroll
    for (int i = tid; i < NV4; i += 256) {
        const int r  = i / (SC / 4);
        const int c4 = (i - r * (SC / 4)) * 4;
        const int gy = oy + r;
        const int gx = ox + c4;           // multiple of 4; fully in or out
        v4 v = 0.f;
        if ((unsigned)gy < (unsigned)H_ && (unsigned)gx < (unsigned)W_)
            v = *reinterpret_cast<const v4*>(dpt + gy * W_ + gx);
        *reinterpret_cast<v4*>(sm + r * SC + c4) = v;
    }

    // ---- batch-prefetch ALL streamed per-pixel values (latency overlaps barrier) ----
    float wt[K_];
#pragma unroll
    for (int k = 0; k < K_; ++k) wt[k] = wtap[k];
    const float bv = bias[0];

    float wg[K_];
    float m = 0.f;
    const float* wbase = weight + (size_t)b * K_ * HW_ + p;
#pragma unroll
    for (int k = 0; k < K_; ++k) {
        wg[k] = wbase[k * HW_];
        m += wg[k];
    }
    m *= (1.f / 9.f);

    float ody[K_], odx[K_];
    const float* obase = offset + (size_t)b * 2 * K_ * HW_ + p;
#pragma unroll
    for (int k = 0; k < K_; ++k) {
        ody[k] = obase[(2 * k) * HW_];
        odx[k] = obase[(2 * k + 1) * HW_];
    }

    __syncthreads();

    const float dval = sm[(ty + SOFF) * SC + (tx + SOFF)];

    float acc = 0.f;
#pragma unroll
    for (int k = 0; k < K_; ++k) {
        const float py = (float)(y + (k / 3) - 1) + ody[k];
        const float px = (float)(x + (k % 3) - 1) + odx[k];
        const float y0f = floorf(py);
        const float x0f = floorf(px);
        const float fy = py - y0f;
        const float fx = px - x0f;
        const int yi0 = (int)y0f, xi0 = (int)x0f;

        const int ly = yi0 - oy;           // need [0, SR-2]
        const int lx = xi0 - ox;           // need [0, SC-2]
        float v00, v01, v10, v11;
        if ((unsigned)ly <= (SR - 2) && (unsigned)lx <= (SC - 2)) {
            const float* s = sm + ly * SC + lx;
            v00 = s[0];
            v01 = s[1];
            v10 = s[SC];
            v11 = s[SC + 1];
        } else {
            // ultra-rare fallback (|offset| > ~7): zero-padded global gather
            const int yi1 = yi0 + 1, xi1 = xi0 + 1;
            const bool vy0 = (unsigned)yi0 < (unsigned)H_;
            const bool vy1 = (unsigned)yi1 < (unsigned)H_;
            const bool vx0 = (unsigned)xi0 < (unsigned)W_;
            const bool vx1 = (unsigned)xi1 < (unsigned)W_;
            const int r0 = yi0 * W_;
            const int r1 = r0 + W_;
            v00 = (vy0 && vx0) ? dpt[r0 + xi0] : 0.f;
            v01 = (vy0 && vx1) ? dpt[r0 + xi1] : 0.f;
            v10 = (vy1 && vx0) ? dpt[r1 + xi0] : 0.f;
            v11 = (vy1 && vx1) ? dpt[r1 + xi1] : 0.f;
        }

        const float gy = 1.f - fy, gx = 1.f - fx;
        const float val = v00 * gy * gx + v01 * gy * fx
                        + v10 * fy * gx + v11 * fy * fx;
        acc += (wg[k] - m) * wt[k] * val;
    }

    out[b * HW_ + p] = acc + bv + dval;
}

extern "C" void kernel_launch(void* const* d_in, const int* in_sizes, int n_in,
                              void* d_out, int out_size, void* d_ws, size_t ws_size,
                              hipStream_t stream) {
    const float* depth  = (const float*)d_in[0];
    const float* weight = (const float*)d_in[1];
    const float* offset = (const float*)d_in[2];
    const float* wtap   = (const float*)d_in[3];
    const float* bias   = (const float*)d_in[4];
    float* out = (float*)d_out;

    dim3 grid(NBLK), block(256);
    hipLaunchKernelGGL(dcn_post_kernel, grid, block, 0, stream,
                       depth, weight, offset, wtap, bias, out);
}